// Round 1
// baseline (107.921 us; speedup 1.0000x reference)
//
#include <hip/hip_runtime.h>
#include <math.h>

#define NW 16
#define NEUR 32
#define GTAB 2048
#define WSUB 0.0625f        // 1/16, exact in fp32
#define INV_SIGMA 200.0f    // 1/0.005
#define OMEGA 15.0f
#define WTHRESH 1e-5f

struct Geo {
    float means[NW];
    float stdv[NW];
    float xlo[NW];
    float h[NW];
};

// Per-window MLP output tabulated on a uniform x-grid over each window's support.
__device__ float g_table[NW * GTAB];

// ---------------- Kernel A: build the per-window u_i(x) table ----------------
// blockIdx.y = window (wave-uniform -> weight reads become scalar s_loads).
__global__ __launch_bounds__(256) void build_table(
    const float* __restrict__ W1, const float* __restrict__ b1,
    const float* __restrict__ W2, const float* __restrict__ b2,
    const float* __restrict__ W3, const float* __restrict__ b3, Geo geo) {
    const int w = blockIdx.y;
    const int g = blockIdx.x * blockDim.x + threadIdx.x;

    const float xg = geo.xlo[w] + geo.h[w] * (float)g;
    const float xn = (xg - geo.means[w]) / geo.stdv[w];

    const float* __restrict__ W1w = W1 + w * NEUR;   // (1,NEUR) row
    const float* __restrict__ b1w = b1 + w * NEUR;
    float h1[NEUR];
#pragma unroll
    for (int j = 0; j < NEUR; ++j)
        h1[j] = tanhf(fmaf(xn, W1w[j], b1w[j]));

    const float* __restrict__ W2w = W2 + w * NEUR * NEUR;  // (NEUR,NEUR), row-major [k][j]
    const float* __restrict__ b2w = b2 + w * NEUR;
    float h2[NEUR];
#pragma unroll 4
    for (int j = 0; j < NEUR; ++j) {
        float acc = b2w[j];
#pragma unroll
        for (int k = 0; k < NEUR; ++k)
            acc = fmaf(h1[k], W2w[k * NEUR + j], acc);
        h2[j] = tanhf(acc);
    }

    const float* __restrict__ W3w = W3 + w * NEUR;   // (NEUR,1)
    float acc = b3[w];
#pragma unroll
    for (int k = 0; k < NEUR; ++k)
        acc = fmaf(h2[k], W3w[k], acc);

    g_table[w * GTAB + g] = acc;   // out*U_SD + U_MEAN with U_SD=1, U_MEAN=0
}

// ---------------- Kernel B: per-point window-weighted lookup ----------------
__device__ __forceinline__ float sigmoid_f(float z) {
    return 1.0f / (1.0f + __expf(-z));
}

__device__ __forceinline__ float eval_point(float x) {
    // Primary interval: exact because *16 is a pure exponent shift in fp32.
    int i0 = (int)(x * 16.0f);
    if (i0 > NW - 1) i0 = NW - 1;

    float pred = 0.0f;
#pragma unroll
    for (int d = -1; d <= 1; ++d) {
        const int c = i0 + d;
        if (c < 0 || c >= NW) continue;
        // mo[c] = c*w exactly (mo[0]=0, mo[16]=1 both match c*w)
        const float mo_lo = (float)c * WSUB;
        const float mo_hi = (float)(c + 1) * WSUB;
        const float s1 = sigmoid_f((x - mo_lo) * INV_SIGMA);
        const float s2 = sigmoid_f(-(x - mo_hi) * INV_SIGMA);
        const float win = s1 * s2;
        if (win > WTHRESH) {
            // Table span: [max(c-1,0)*w, min(c+2,16)*w]
            const int clo = (c >= 1) ? (c - 1) : 0;
            const int chi = (c <= 14) ? (c + 2) : 16;
            const float xlo = (float)clo * WSUB;
            const float invh = (float)(GTAB - 1) / ((float)(chi - clo) * WSUB);
            float t = (x - xlo) * invh;
            t = fminf(fmaxf(t, 0.0f), (float)(GTAB - 1));
            int it = (int)t;
            if (it > GTAB - 2) it = GTAB - 2;
            const float f = t - (float)it;
            const float u0 = g_table[c * GTAB + it];
            const float u1 = g_table[c * GTAB + it + 1];
            pred = fmaf(win, fmaf(f, u1 - u0, u0), pred);
        }
    }
    // hard constraint tanh(15x); x >= 0 so exp(30x) is safe in fp32
    const float e = __expf(2.0f * OMEGA * x);
    const float th = 1.0f - 2.0f / (e + 1.0f);
    return th * pred;
}

__global__ __launch_bounds__(256) void fbpinn_eval(
    const float* __restrict__ x, float* __restrict__ out, int n) {
    const int idx = blockIdx.x * blockDim.x + threadIdx.x;
    const int i4 = idx * 4;
    if (i4 + 3 < n) {
        const float4 xv = *(const float4*)(x + i4);
        float4 r;
        r.x = eval_point(xv.x);
        r.y = eval_point(xv.y);
        r.z = eval_point(xv.z);
        r.w = eval_point(xv.w);
        *(float4*)(out + i4) = r;
    } else {
        for (int i = i4; i < n; ++i) out[i] = eval_point(x[i]);
    }
}

extern "C" void kernel_launch(void* const* d_in, const int* in_sizes, int n_in,
                              void* d_out, int out_size, void* d_ws, size_t ws_size,
                              hipStream_t stream) {
    const float* x  = (const float*)d_in[0];
    const float* W1 = (const float*)d_in[1];
    const float* b1 = (const float*)d_in[2];
    const float* W2 = (const float*)d_in[3];
    const float* b2 = (const float*)d_in[4];
    const float* W3 = (const float*)d_in[5];
    const float* b3 = (const float*)d_in[6];
    float* out = (float*)d_out;
    const int n = in_sizes[0];

    // Host-side geometry in double, cast to fp32 (matches reference _geometry()).
    Geo geo;
    const double w = 1.0 / (double)NW;
    for (int i = 0; i < NW; ++i) {
        const double s0 = (i == 0)      ? 0.0 : (i - 0.125) * w;
        const double s1 = (i == NW - 1) ? 1.0 : (i + 1 + 0.125) * w;
        geo.means[i] = (float)((s0 + s1) * 0.5);
        geo.stdv[i]  = (float)((s1 - s0) * 0.5);
        const int clo = (i >= 1) ? (i - 1) : 0;
        const int chi = (i <= NW - 2) ? (i + 2) : NW;
        const double xlo = clo * w;
        const double xhi = chi * w;
        geo.xlo[i] = (float)xlo;
        geo.h[i]   = (float)((xhi - xlo) / (double)(GTAB - 1));
    }

    build_table<<<dim3(GTAB / 256, NW), 256, 0, stream>>>(W1, b1, W2, b2, W3, b3, geo);

    const int n4 = (n + 3) / 4;
    const int blocks = (n4 + 255) / 256;
    fbpinn_eval<<<blocks, 256, 0, stream>>>(x, out, n);
}

// Round 2
// 107.849 us; speedup vs baseline: 1.0007x; 1.0007x over previous
//
#include <hip/hip_runtime.h>
#include <math.h>

#define NW 16
#define NEUR 32
#define GTAB 1024
#define WSUB 0.0625f        // 1/16, exact in fp32
#define INV_SIGMA 200.0f    // 1/0.005
#define OMEGA 15.0f
#define WTHRESH 1e-5f
#define EVAL_BLOCKS 512
#define EVAL_THREADS 256

struct Geo {
    float means[NW];
    float stdv[NW];
    float xlo[NW];
    float h[NW];
};

// Per-window MLP output tabulated on a uniform x-grid over each window's support.
__device__ float g_table[NW * GTAB];   // 64 KB

// ---------------- Kernel A: build the per-window u_i(x) table ----------------
// blockIdx.y = window (wave-uniform -> weight reads become scalar s_loads).
__global__ __launch_bounds__(256) void build_table(
    const float* __restrict__ W1, const float* __restrict__ b1,
    const float* __restrict__ W2, const float* __restrict__ b2,
    const float* __restrict__ W3, const float* __restrict__ b3, Geo geo) {
    const int w = blockIdx.y;
    const int g = blockIdx.x * blockDim.x + threadIdx.x;

    const float xg = geo.xlo[w] + geo.h[w] * (float)g;
    const float xn = (xg - geo.means[w]) / geo.stdv[w];

    const float* __restrict__ W1w = W1 + w * NEUR;   // (1,NEUR) row
    const float* __restrict__ b1w = b1 + w * NEUR;
    float h1[NEUR];
#pragma unroll
    for (int j = 0; j < NEUR; ++j)
        h1[j] = tanhf(fmaf(xn, W1w[j], b1w[j]));

    const float* __restrict__ W2w = W2 + w * NEUR * NEUR;  // (NEUR,NEUR), row-major [k][j]
    const float* __restrict__ b2w = b2 + w * NEUR;
    float h2[NEUR];
#pragma unroll 4
    for (int j = 0; j < NEUR; ++j) {
        float acc = b2w[j];
#pragma unroll
        for (int k = 0; k < NEUR; ++k)
            acc = fmaf(h1[k], W2w[k * NEUR + j], acc);
        h2[j] = tanhf(acc);
    }

    const float* __restrict__ W3w = W3 + w * NEUR;   // (NEUR,1)
    float acc = b3[w];
#pragma unroll
    for (int k = 0; k < NEUR; ++k)
        acc = fmaf(h2[k], W3w[k], acc);

    g_table[w * GTAB + g] = acc;   // out*U_SD + U_MEAN with U_SD=1, U_MEAN=0
}

// ---------------- Kernel B: per-point window-weighted lookup ----------------
__device__ __forceinline__ float sigmoid_f(float z) {
    return 1.0f / (1.0f + __expf(-z));
}

__device__ __forceinline__ float eval_point(float x, const float* __restrict__ tab) {
    // Primary interval: exact because *16 is a pure exponent shift in fp32.
    int i0 = (int)(x * 16.0f);
    if (i0 > NW - 1) i0 = NW - 1;

    // Shared boundary sigmoids: sig[k] = sigmoid((x - (i0-1+k)*w)/sigma), k=0..3
    // Window c = i0-1+d has win = sig[d] * (1 - sig[d+1]).
    float sig[4];
#pragma unroll
    for (int k = 0; k < 4; ++k) {
        const float mo = (float)(i0 - 1 + k) * WSUB;
        sig[k] = sigmoid_f((x - mo) * INV_SIGMA);
    }

    float pred = 0.0f;
#pragma unroll
    for (int d = 0; d < 3; ++d) {
        const int c = i0 - 1 + d;
        if (c < 0 || c >= NW) continue;
        const float win = sig[d] * (1.0f - sig[d + 1]);
        if (win > WTHRESH) {
            // Table span for window c: [max(c-1,0)*w, min(c+2,16)*w]
            const int clo = (c >= 1) ? (c - 1) : 0;
            const int chi = (c <= 14) ? (c + 2) : 16;
            const float xlo = (float)clo * WSUB;
            const float invh = (float)(GTAB - 1) / ((float)(chi - clo) * WSUB);
            float t = (x - xlo) * invh;
            t = fminf(fmaxf(t, 0.0f), (float)(GTAB - 1));
            int it = (int)t;
            if (it > GTAB - 2) it = GTAB - 2;
            const float f = t - (float)it;
            const float u0 = tab[c * GTAB + it];
            const float u1 = tab[c * GTAB + it + 1];
            pred = fmaf(win, fmaf(f, u1 - u0, u0), pred);
        }
    }
    // hard constraint tanh(15x); x >= 0 so exp(30x) is safe in fp32
    const float e = __expf(2.0f * OMEGA * x);
    const float th = 1.0f - 2.0f / (e + 1.0f);
    return th * pred;
}

__global__ __launch_bounds__(EVAL_THREADS) void fbpinn_eval(
    const float* __restrict__ x, float* __restrict__ out, int n) {
    __shared__ float s_tab[NW * GTAB];   // 64 KB -> 2 blocks/CU

    // Stage the whole table into LDS (coalesced float4).
    {
        const float4* __restrict__ src = (const float4*)g_table;
        float4* dst = (float4*)s_tab;
#pragma unroll
        for (int i = threadIdx.x; i < NW * GTAB / 4; i += EVAL_THREADS)
            dst[i] = src[i];
    }
    __syncthreads();

    const int n4 = n >> 2;              // full float4 groups
    const int stride = gridDim.x * blockDim.x;
    for (int idx = blockIdx.x * blockDim.x + threadIdx.x; idx < n4; idx += stride) {
        const float4 xv = *(const float4*)(x + idx * 4);
        float4 r;
        r.x = eval_point(xv.x, s_tab);
        r.y = eval_point(xv.y, s_tab);
        r.z = eval_point(xv.z, s_tab);
        r.w = eval_point(xv.w, s_tab);
        *(float4*)(out + idx * 4) = r;
    }
    // Tail (n not multiple of 4): first few threads of block 0.
    if (blockIdx.x == 0) {
        const int tail = n & 3;
        if ((int)threadIdx.x < tail)
            out[n4 * 4 + threadIdx.x] = eval_point(x[n4 * 4 + threadIdx.x], s_tab);
    }
}

extern "C" void kernel_launch(void* const* d_in, const int* in_sizes, int n_in,
                              void* d_out, int out_size, void* d_ws, size_t ws_size,
                              hipStream_t stream) {
    const float* x  = (const float*)d_in[0];
    const float* W1 = (const float*)d_in[1];
    const float* b1 = (const float*)d_in[2];
    const float* W2 = (const float*)d_in[3];
    const float* b2 = (const float*)d_in[4];
    const float* W3 = (const float*)d_in[5];
    const float* b3 = (const float*)d_in[6];
    float* out = (float*)d_out;
    const int n = in_sizes[0];

    // Host-side geometry in double, cast to fp32 (matches reference _geometry()).
    Geo geo;
    const double w = 1.0 / (double)NW;
    for (int i = 0; i < NW; ++i) {
        const double s0 = (i == 0)      ? 0.0 : (i - 0.125) * w;
        const double s1 = (i == NW - 1) ? 1.0 : (i + 1 + 0.125) * w;
        geo.means[i] = (float)((s0 + s1) * 0.5);
        geo.stdv[i]  = (float)((s1 - s0) * 0.5);
        const int clo = (i >= 1) ? (i - 1) : 0;
        const int chi = (i <= NW - 2) ? (i + 2) : NW;
        const double xlo = clo * w;
        const double xhi = chi * w;
        geo.xlo[i] = (float)xlo;
        geo.h[i]   = (float)((xhi - xlo) / (double)(GTAB - 1));
    }

    build_table<<<dim3(GTAB / 256, NW), 256, 0, stream>>>(W1, b1, W2, b2, W3, b3, geo);

    fbpinn_eval<<<EVAL_BLOCKS, EVAL_THREADS, 0, stream>>>(x, out, n);
}

// Round 3
// 101.967 us; speedup vs baseline: 1.0584x; 1.0577x over previous
//
#include <hip/hip_runtime.h>
#include <math.h>

#define NW 16
#define NEUR 32
#define TTAB 8192            // global F-table nodes over [0,1]
#define WSUB 0.0625f         // 1/16, exact in fp32
#define INV_SIGMA 200.0f     // 1/0.005
#define OMEGA 15.0f
#define WTHRESH 1e-5f
#define EVAL_BLOCKS 512
#define EVAL_THREADS 256

__device__ __forceinline__ float sigmoid_f(float z) {
    return 1.0f / (1.0f + __expf(-z));
}
__device__ __forceinline__ float tanh_fast(float z) {
    // z bounded (~|z|<40 here); tanh = 1 - 2/(e^{2z}+1)
    const float e = __expf(2.0f * z);
    return 1.0f - 2.0f / (e + 1.0f);
}

// ---------- K1: build partial[d][g] = win_c(x_g) * u_c(x_g), c = i0(g)-1+d ----------
// grid (TTAB/256, 3). Within a block, g is contiguous -> c nearly wave-uniform
// -> weight loads are cache-broadcast. means/std are exact dyadic constants.
__global__ __launch_bounds__(256) void build_F(
    const float* __restrict__ W1, const float* __restrict__ b1,
    const float* __restrict__ W2, const float* __restrict__ b2,
    const float* __restrict__ W3, const float* __restrict__ b3,
    float* __restrict__ partial) {
    const int d = blockIdx.y;                       // 0,1,2
    const int g = blockIdx.x * blockDim.x + threadIdx.x;

    const float x = (float)g * (1.0f / (float)(TTAB - 1));
    int i0 = (int)(x * 16.0f);
    if (i0 > NW - 1) i0 = NW - 1;
    const int c = i0 - 1 + d;

    float val = 0.0f;
    if (c >= 0 && c < NW) {
        const float s1 = sigmoid_f((x - (float)c * WSUB) * INV_SIGMA);
        const float s2 = sigmoid_f(-(x - (float)(c + 1) * WSUB) * INV_SIGMA);
        const float win = s1 * s2;
        if (win > WTHRESH) {
            // subdomain normalization constants (exact dyadic, match reference fp64->fp32)
            float mean, sd;
            if (c == 0)            { mean = 0.03515625f; sd = 0.03515625f; }
            else if (c == NW - 1)  { mean = 0.96484375f; sd = 0.03515625f; }
            else                   { mean = ((float)c + 0.5f) * 0.0625f; sd = 0.0390625f; }
            const float xn = (x - mean) / sd;

            const float* __restrict__ W1c = W1 + c * NEUR;
            const float* __restrict__ b1c = b1 + c * NEUR;
            float h1[NEUR];
#pragma unroll
            for (int j = 0; j < NEUR; ++j)
                h1[j] = tanh_fast(fmaf(xn, W1c[j], b1c[j]));

            const float* __restrict__ W2c = W2 + c * NEUR * NEUR;  // [k][j]
            const float* __restrict__ b2c = b2 + c * NEUR;
            float h2[NEUR];
#pragma unroll
            for (int j = 0; j < NEUR; ++j) h2[j] = b2c[j];
#pragma unroll 4
            for (int k = 0; k < NEUR; ++k) {
                const float hk = h1[k];
                const float4* __restrict__ row = (const float4*)(W2c + k * NEUR);
#pragma unroll
                for (int q = 0; q < NEUR / 4; ++q) {
                    const float4 wv = row[q];
                    h2[q * 4 + 0] = fmaf(hk, wv.x, h2[q * 4 + 0]);
                    h2[q * 4 + 1] = fmaf(hk, wv.y, h2[q * 4 + 1]);
                    h2[q * 4 + 2] = fmaf(hk, wv.z, h2[q * 4 + 2]);
                    h2[q * 4 + 3] = fmaf(hk, wv.w, h2[q * 4 + 3]);
                }
            }

            const float* __restrict__ W3c = W3 + c * NEUR;
            float acc = b3[c];
#pragma unroll
            for (int k = 0; k < NEUR; ++k)
                acc = fmaf(tanh_fast(h2[k]), W3c[k], acc);

            val = win * acc;   // U_SD=1, U_MEAN=0
        }
    }
    partial[d * TTAB + g] = val;
}

// ---------- K2: F = sum(partial) into LDS; per point one lerp + tanh(15x) ----------
__global__ __launch_bounds__(EVAL_THREADS) void eval_F(
    const float* __restrict__ x, const float* __restrict__ partial,
    float* __restrict__ out, int n) {
    __shared__ float F[TTAB];   // 32 KB

    {
        const float4* __restrict__ p = (const float4*)partial;
        float4* Fv = (float4*)F;
        const int Q = TTAB / 4;
#pragma unroll
        for (int i = threadIdx.x; i < Q; i += EVAL_THREADS) {
            const float4 a = p[i];
            const float4 b = p[i + Q];
            const float4 c = p[i + 2 * Q];
            float4 r;
            r.x = a.x + b.x + c.x;
            r.y = a.y + b.y + c.y;
            r.z = a.z + b.z + c.z;
            r.w = a.w + b.w + c.w;
            Fv[i] = r;
        }
    }
    __syncthreads();

    const int n4 = n >> 2;
    const int stride = gridDim.x * blockDim.x;
    for (int idx = blockIdx.x * blockDim.x + threadIdx.x; idx < n4; idx += stride) {
        const float4 xv = *(const float4*)(x + idx * 4);
        float4 r;
#pragma unroll
        for (int e = 0; e < 4; ++e) {
            const float xe = (&xv.x)[e];
            float t = xe * (float)(TTAB - 1);
            t = fminf(fmaxf(t, 0.0f), (float)(TTAB - 1) - 0.5f);
            const int it = (int)t;
            const float f = t - (float)it;
            const float u0 = F[it];
            const float u1 = F[it + 1];
            const float u = fmaf(f, u1 - u0, u0);
            (&r.x)[e] = tanh_fast(OMEGA * xe) * u;
        }
        *(float4*)(out + idx * 4) = r;
    }
    if (blockIdx.x == 0) {
        const int tail = n & 3;
        if ((int)threadIdx.x < tail) {
            const float xe = x[n4 * 4 + threadIdx.x];
            float t = xe * (float)(TTAB - 1);
            t = fminf(fmaxf(t, 0.0f), (float)(TTAB - 1) - 0.5f);
            const int it = (int)t;
            const float f = t - (float)it;
            const float u = fmaf(f, F[it + 1] - F[it], F[it]);
            out[n4 * 4 + threadIdx.x] = tanh_fast(OMEGA * xe) * u;
        }
    }
}

extern "C" void kernel_launch(void* const* d_in, const int* in_sizes, int n_in,
                              void* d_out, int out_size, void* d_ws, size_t ws_size,
                              hipStream_t stream) {
    const float* x  = (const float*)d_in[0];
    const float* W1 = (const float*)d_in[1];
    const float* b1 = (const float*)d_in[2];
    const float* W2 = (const float*)d_in[3];
    const float* b2 = (const float*)d_in[4];
    const float* W3 = (const float*)d_in[5];
    const float* b3 = (const float*)d_in[6];
    float* out = (float*)d_out;
    float* partial = (float*)d_ws;   // 3 * TTAB floats = 96 KB
    const int n = in_sizes[0];

    build_F<<<dim3(TTAB / 256, 3), 256, 0, stream>>>(W1, b1, W2, b2, W3, b3, partial);
    eval_F<<<EVAL_BLOCKS, EVAL_THREADS, 0, stream>>>(x, partial, out, n);
}